// Round 3
// baseline (893.084 us; speedup 1.0000x reference)
//
#include <hip/hip_runtime.h>
#include <stdint.h>

// SchNet on MI355X (gfx950). Structure:
//  - W(d)*C(d) filter tabulated on 4096-bin grid (f16) -> kills 113 GFLOP edge MLP.
//  - Edges counting-sorted by dst, packed (src<<15|dist_q15) -> per-dst register
//    accumulation, no f32 atomics, 4B/edge sorted reads.
//  - Dense [N,128] GEMMs via mfma_f32_16x16x32_f16, weights transposed in LDS (pad 136).
//  - R3: runtime dtype detection (bf16 vs f32 float inputs) — R1/R2 NaN is consistent
//    with reading f32 buffers as bf16 pairs; detection makes both stories correct.
//    Sub-array offsets (per-interaction weights) are passed as ELEMENT offsets and
//    resolved inside ldf(), so they are dtype-size-correct.

#define NBINS 4096
#define NROWS (NBINS + 1)
#define DMAXV 8.6610f   // slightly above sqrt(75)=8.66025

typedef _Float16 half8 __attribute__((ext_vector_type(8)));
typedef _Float16 h2 __attribute__((ext_vector_type(2)));
typedef float f32x4 __attribute__((ext_vector_type(4)));

__device__ __forceinline__ float bf2f(unsigned short u) {
  union { uint32_t i; float f; } v; v.i = ((uint32_t)u) << 16; return v.f;
}
__device__ __forceinline__ unsigned short f2bf(float f) {
  union { float f; uint32_t i; } v; v.f = f;
  uint32_t u = v.i;
  return (unsigned short)((u + 0x7fffu + ((u >> 16) & 1u)) >> 16);
}
// dual-dtype float load: isbf=1 -> bf16 u16 array, isbf=0 -> f32 array
__device__ __forceinline__ float ldf(const void* p, size_t i, int isbf) {
  if (isbf) return bf2f(((const unsigned short*)p)[i]);
  return ((const float*)p)[i];
}
__device__ __forceinline__ float sspf(float x) {
  float sp = (x > 15.0f) ? x : log1pf(expf(x));
  return sp - 0.6931471805599453f;
}

// ---------------- dtype detection: even u16s of emb are bf16-plausible iff bf16
__global__ void detect_kernel(const unsigned short* __restrict__ emb,
                              int* __restrict__ flag) {
  if (threadIdx.x == 0) {
    int score = 0;
    for (int i = 0; i < 64; i++) {
      unsigned short u = emb[2 * i];
      int e = (u >> 7) & 0xFF;
      if (e >= 100 && e <= 126) score++;
    }
    *flag = (score >= 32) ? 1 : 0;
  }
}

// ---------------- filter table: table[i][k][h] = (ssp(rbf@w1+b1)@w2+b2)*C, f16
__global__ __launch_bounds__(128) void table_kernel(
    const void* __restrict__ w1, const void* __restrict__ b1,
    const void* __restrict__ w2, const void* __restrict__ b2,
    _Float16* __restrict__ tables, const int* __restrict__ flag) {
  int isbf = *flag;
  int blk = blockIdx.x;
  int i = blk / NROWS, k = blk % NROWS;
  int hh = threadIdx.x;
  float d = (float)k * (DMAXV / (float)NBINS);
  const float delta = 10.0f / 9.0f;
  const float coeff = -0.5f / (delta * delta);
  float u = ldf(b1, i * 128 + hh, isbf);
  #pragma unroll
  for (int g = 0; g < 10; g++) {
    float off = (float)g * delta;
    float r = expf(coeff * (d - off) * (d - off));
    u += r * ldf(w1, (size_t)(i * 10 + g) * 128 + hh, isbf);
  }
  __shared__ float a[128];
  a[hh] = sspf(u);
  __syncthreads();
  float W = ldf(b2, i * 128 + hh, isbf);
  for (int h2i = 0; h2i < 128; h2i++)
    W += a[h2i] * ldf(w2, (size_t)(i * 128 + h2i) * 128 + hh, isbf);
  float C = 0.5f * (cosf(d * 3.14159265358979323846f / 10.0f) + 1.0f);
  tables[((size_t)i * NROWS + k) * 128 + hh] = (_Float16)(W * C);
}

// ---------------- edge pass 1: dst histogram only
__global__ __launch_bounds__(256) void edge_pass1_kernel(
    const int* __restrict__ ei, int* __restrict__ count, int E) {
  int e = blockIdx.x * 256 + threadIdx.x;
  if (e >= E) return;
  atomicAdd(&count[ei[E + e]], 1);
}

// ---------------- exclusive scan of count[N] -> offs[N+1] (single block)
__global__ __launch_bounds__(1024) void scan_kernel(
    const int* __restrict__ count, int* __restrict__ offs, int n) {
  __shared__ int part[1024];
  int t = threadIdx.x;
  int C = (n + 1023) / 1024;
  int b0 = t * C, b1 = min(b0 + C, n);
  int s = 0;
  for (int i = b0; i < b1; i++) s += count[i];
  int v = s;
  part[t] = v;
  __syncthreads();
  for (int off = 1; off < 1024; off <<= 1) {
    int u = (t >= off) ? part[t - off] : 0;
    __syncthreads();
    v += u;
    part[t] = v;
    __syncthreads();
  }
  int run = v - s;  // exclusive base
  if (b0 < n) {
    for (int i = b0; i < b1; i++) { offs[i] = run; run += count[i]; }
  }
  if (t == 1023) offs[n] = v;
}

// ---------------- edge pass 2: distance, place packed (src<<15 | q15) by dst
__global__ __launch_bounds__(256) void edge_pass2_kernel(
    const int* __restrict__ ei, const void* __restrict__ pos,
    const int* __restrict__ offs, int* __restrict__ cur,
    unsigned int* __restrict__ pk, int E, const int* __restrict__ flag) {
  int isbf = *flag;
  int e = blockIdx.x * 256 + threadIdx.x;
  if (e >= E) return;
  int s = ei[e], d = ei[E + e];
  float ax = ldf(pos, s * 3 + 0, isbf), ay = ldf(pos, s * 3 + 1, isbf), az = ldf(pos, s * 3 + 2, isbf);
  float bx = ldf(pos, d * 3 + 0, isbf), by = ldf(pos, d * 3 + 1, isbf), bz = ldf(pos, d * 3 + 2, isbf);
  float dx = ax - bx, dy = ay - by, dz = az - bz;
  float dist = sqrtf(dx * dx + dy * dy + dz * dz);
  int q = (int)(dist * (32768.0f / DMAXV));
  if (q > 32767) q = 32767;
  int p = offs[d] + atomicAdd(&cur[d], 1);
  pk[p] = ((unsigned int)s << 15) | (unsigned int)q;
}

// ---------------- h = emb[z]  (f16 out)
__global__ __launch_bounds__(256) void embed_kernel(
    const void* __restrict__ emb, const int* __restrict__ z,
    _Float16* __restrict__ h, int total, const int* __restrict__ flag) {
  int isbf = *flag;
  int i = blockIdx.x * 256 + threadIdx.x;
  if (i >= total) return;
  int n = i >> 7, c = i & 127;
  h[i] = (_Float16)ldf(emb, (size_t)z[n] * 128 + c, isbf);
}

// ---------------- GEMM: out[N,MD] = op(A[N,KD] @ W[KD,MD] (+bias)) (+resid)
// W/bias passed as base + ELEMENT offset (dtype-size resolved in ldf).
template <int KD, int MD, bool BIAS, bool ACT, bool RES>
__global__ __launch_bounds__(256) void gemm_kernel(
    const _Float16* __restrict__ A, const void* __restrict__ W, size_t woff,
    const void* __restrict__ bias, size_t boff, const _Float16* __restrict__ resid,
    _Float16* __restrict__ out, int nrows, const int* __restrict__ flag) {
  int isbf = *flag;
  __shared__ __align__(16) _Float16 wT[MD][136];  // transposed, +8 pad (16B mod 128B)
  int t = threadIdx.x;
  for (int idx = t; idx < KD * MD; idx += 256) {
    int k = idx / MD, m = idx - k * MD;
    wT[m][k] = (_Float16)ldf(W, woff + idx, isbf);
  }
  __syncthreads();
  int wave = t >> 6, lane = t & 63;
  int quad = lane >> 4, l16 = lane & 15;
  int row0 = blockIdx.x * 64 + wave * 16;
  constexpr int NT = MD / 16;
  f32x4 acc[NT] = {};
  int arow = row0 + l16;
  if (arow >= nrows) arow = nrows - 1;  // clamp: D row m depends only on A row m
  const _Float16* ap = A + (size_t)arow * KD;
  #pragma unroll
  for (int ks = 0; ks < KD / 32; ks++) {
    int kb = ks * 32 + quad * 8;
    half8 af = *(const half8*)(ap + kb);
    #pragma unroll
    for (int ct = 0; ct < NT; ct++) {
      half8 bfr = *(const half8*)&wT[ct * 16 + l16][kb];
      acc[ct] = __builtin_amdgcn_mfma_f32_16x16x32_f16(af, bfr, acc[ct], 0, 0, 0);
    }
  }
  #pragma unroll
  for (int ct = 0; ct < NT; ct++) {
    int col = ct * 16 + l16;
    float bv = BIAS ? ldf(bias, boff + col, isbf) : 0.0f;
    #pragma unroll
    for (int r = 0; r < 4; r++) {
      int row = row0 + quad * 4 + r;
      if (row < nrows) {
        float v = acc[ct][r] + bv;
        if (ACT) v = sspf(v);
        if (RES) v += (float)resid[(size_t)row * MD + col];
        out[(size_t)row * MD + col] = (_Float16)v;
      }
    }
  }
}

// ---------------- CFConv aggregate: one wave per dst, register accumulation
__global__ __launch_bounds__(256) void aggregate_kernel(
    const _Float16* __restrict__ xj, const _Float16* __restrict__ table,
    const unsigned int* __restrict__ pk,
    const int* __restrict__ offs, _Float16* __restrict__ agg, int n) {
  int wave = threadIdx.x >> 6, lane = threadIdx.x & 63;
  int dst = blockIdx.x * 4 + wave;
  if (dst >= n) return;
  int beg = offs[dst], end = offs[dst + 1];
  float accx = 0.f, accy = 0.f;
  int c2 = lane * 2;
  for (int e0 = beg; e0 < end; e0 += 64) {
    int cnt = end - e0;
    if (cnt > 64) cnt = 64;
    unsigned int pv = 0;
    if (lane < cnt) pv = pk[e0 + lane];
    for (int k = 0; k < cnt; k++) {
      unsigned int v = (unsigned int)__shfl((int)pv, k);
      int src = (int)(v >> 15);
      float x = (float)(v & 32767u) * (4096.0f / 32768.0f);
      int bin = (int)x;
      float f = x - (float)bin;
      h2 t0 = *(const h2*)(table + ((size_t)bin << 7) + c2);
      h2 t1 = *(const h2*)(table + (((size_t)bin + 1) << 7) + c2);
      h2 xv = *(const h2*)(xj + ((size_t)src << 7) + c2);
      float w0 = (float)t0.x + f * ((float)t1.x - (float)t0.x);
      float w1v = (float)t0.y + f * ((float)t1.y - (float)t0.y);
      accx += (float)xv.x * w0;
      accy += (float)xv.y * w1v;
    }
  }
  h2 o; o.x = (_Float16)accx; o.y = (_Float16)accy;
  *(h2*)(agg + ((size_t)dst << 7) + c2) = o;
}

// ---------------- batch pooling (batch is sorted): per-block run-length sums
__global__ __launch_bounds__(128) void pool_kernel(
    const _Float16* __restrict__ t2, const int* __restrict__ batch,
    float* __restrict__ pooled, int n) {
  int c = threadIdx.x;
  int r0 = blockIdx.x * 128, r1 = min(r0 + 128, n);
  float acc = 0.f;
  int cur = batch[r0];
  for (int r = r0; r < r1; r++) {
    int b = batch[r];  // wave-uniform
    if (b != cur) { atomicAdd(&pooled[cur * 128 + c], acc); acc = 0.f; cur = b; }
    acc += (float)t2[(size_t)r * 128 + c];
  }
  atomicAdd(&pooled[cur * 128 + c], acc);
}

// ---------------- final: out[B,4] = pooled @ pred_w + pred_b (dual-dtype out)
__global__ __launch_bounds__(256) void final_kernel(
    const float* __restrict__ pooled, const void* __restrict__ pw,
    const void* __restrict__ pb, void* __restrict__ out,
    int total, const int* __restrict__ flag) {
  int isbf = *flag;
  int t = threadIdx.x;
  if (t >= total) return;
  int b = t >> 2, j = t & 3;
  float s = ldf(pb, j, isbf);
  for (int k = 0; k < 128; k++) s += pooled[b * 128 + k] * ldf(pw, k * 4 + j, isbf);
  if (isbf) ((unsigned short*)out)[t] = f2bf(s);
  else      ((float*)out)[t] = s;
}

extern "C" void kernel_launch(void* const* d_in, const int* in_sizes, int n_in,
                              void* d_out, int out_size, void* d_ws, size_t ws_size,
                              hipStream_t stream) {
  const int* z    = (const int*)d_in[0];
  const void* pos = d_in[1];
  const int* batch = (const int*)d_in[2];
  const int* ei   = (const int*)d_in[3];
  const void* emb  = d_in[4];
  const void* w1   = d_in[5];
  const void* b1   = d_in[6];
  const void* w2   = d_in[7];
  const void* b2   = d_in[8];
  const void* lin1 = d_in[9];
  const void* lin2 = d_in[10];
  const void* lin2b= d_in[11];
  const void* linw = d_in[12];
  const void* linb = d_in[13];
  const void* o1w  = d_in[14];
  const void* o1b  = d_in[15];
  const void* o2w  = d_in[16];
  const void* o2b  = d_in[17];
  const void* pw   = d_in[18];
  const void* pb   = d_in[19];

  int N = in_sizes[0];
  int E = in_sizes[3] / 2;

  // workspace carve (256B aligned). Total ~47.5 MB.
  char* p = (char*)d_ws;
  auto carve = [&](size_t bytes) -> void* {
    void* r = (void*)p;
    p += (bytes + 255) & ~(size_t)255;
    return r;
  };
  int*      flag   = (int*)carve(256);
  _Float16* tables = (_Float16*)carve((size_t)2 * NROWS * 128 * 2);  // 2.0 MB
  unsigned int* pk = (unsigned int*)carve((size_t)E * 4);            // 6.4 MB
  int*   offs   = (int*)carve((size_t)(N + 1) * 4);
  char*  zbase  = p;                                                 // zero-init start
  int*   count  = (int*)carve((size_t)N * 4);
  int*   count2 = (int*)carve((size_t)N * 4);
  float* pooled = (float*)carve((size_t)64 * 128 * 4);
  size_t zbytes = (size_t)(p - zbase);
  _Float16* h   = (_Float16*)carve((size_t)N * 128 * 2);             // 12.8 MB
  _Float16* xj  = (_Float16*)carve((size_t)N * 128 * 2);             // 12.8 MB (also t1)
  _Float16* agg = (_Float16*)carve((size_t)N * 128 * 2);             // 12.8 MB (also t2)

  hipMemsetAsync(zbase, 0, zbytes, stream);
  detect_kernel<<<1, 64, 0, stream>>>((const unsigned short*)emb, flag);

  table_kernel<<<2 * NROWS, 128, 0, stream>>>(w1, b1, w2, b2, tables, flag);
  edge_pass1_kernel<<<(E + 255) / 256, 256, 0, stream>>>(ei, count, E);
  scan_kernel<<<1, 1024, 0, stream>>>(count, offs, N);
  edge_pass2_kernel<<<(E + 255) / 256, 256, 0, stream>>>(ei, pos, offs, count2, pk, E, flag);
  embed_kernel<<<(N * 128 + 255) / 256, 256, 0, stream>>>(emb, z, h, N * 128, flag);

  int gblocks = (N + 63) / 64;
  for (int i = 0; i < 2; i++) {
    size_t wo = (size_t)i * 128 * 128;   // element offsets
    size_t bo = (size_t)i * 128;
    gemm_kernel<128, 128, false, false, false><<<gblocks, 256, 0, stream>>>(
        h, lin1, wo, nullptr, 0, nullptr, xj, N, flag);
    aggregate_kernel<<<(N + 3) / 4, 256, 0, stream>>>(
        xj, tables + (size_t)i * NROWS * 128, pk, offs, agg, N);
    gemm_kernel<128, 128, true, true, false><<<gblocks, 256, 0, stream>>>(
        agg, lin2, wo, lin2b, bo, nullptr, xj, N, flag);
    gemm_kernel<128, 128, true, false, true><<<gblocks, 256, 0, stream>>>(
        xj, linw, wo, linb, bo, h, h, N, flag);
  }

  gemm_kernel<128, 64, true, true, false><<<gblocks, 256, 0, stream>>>(
      h, o1w, 0, o1b, 0, nullptr, xj, N, flag);           // t1 = ssp(h@out1+b) [N,64]
  gemm_kernel<64, 128, true, false, false><<<gblocks, 256, 0, stream>>>(
      xj, o2w, 0, o2b, 0, nullptr, agg, N, flag);         // t2 = t1@out2+b [N,128]
  pool_kernel<<<(N + 127) / 128, 128, 0, stream>>>(agg, batch, pooled, N);
  final_kernel<<<1, 256, 0, stream>>>(pooled, pw, pb, d_out, out_size, flag);
}

// Round 4
// 732.793 us; speedup vs baseline: 1.2187x; 1.2187x over previous
//
#include <hip/hip_runtime.h>
#include <stdint.h>

// SchNet on MI355X (gfx950). R4:
//  - aggregate: nearest-bin table (no lerp, 2 loads/edge), pk=(src<<13|bin) read as
//    wave-uniform broadcast load (no ds_bpermute), unroll 2. Was 110us ea, VALU 60%.
//  - GEMM: weights pre-transposed to f16 once (prep), b128 vector LDS staging,
//    2x8 register blocking (2 MFMA per ds_read_b128), 128 rows/block.
//  - table: rbf+ssp act kernel -> fast GEMM with cos-envelope epilogue (CMUL).
//  - scan: 3-phase coalesced. detect: parallel ballot.
// Dual-dtype inputs (bf16 or f32) resolved at runtime via detect_kernel.

#define NBINS 4096
#define NROWS (NBINS + 1)
#define DMAXV 8.6610f   // slightly above sqrt(75)=8.66025

typedef _Float16 half8 __attribute__((ext_vector_type(8)));
typedef _Float16 h2 __attribute__((ext_vector_type(2)));
typedef float f32x4 __attribute__((ext_vector_type(4)));

__device__ __forceinline__ float bf2f(unsigned short u) {
  union { uint32_t i; float f; } v; v.i = ((uint32_t)u) << 16; return v.f;
}
__device__ __forceinline__ unsigned short f2bf(float f) {
  union { float f; uint32_t i; } v; v.f = f;
  uint32_t u = v.i;
  return (unsigned short)((u + 0x7fffu + ((u >> 16) & 1u)) >> 16);
}
__device__ __forceinline__ float ldf(const void* p, size_t i, int isbf) {
  if (isbf) return bf2f(((const unsigned short*)p)[i]);
  return ((const float*)p)[i];
}
__device__ __forceinline__ float sspf(float x) {
  float sp = (x > 15.0f) ? x : log1pf(expf(x));
  return sp - 0.6931471805599453f;
}

// ---------------- dtype detection (parallel, ballot)
__global__ void detect_kernel(const unsigned short* __restrict__ emb,
                              int* __restrict__ flag) {
  int i = threadIdx.x;
  unsigned short u = emb[2 * i];
  int e = (u >> 7) & 0xFF;
  unsigned long long m = __ballot(e >= 100 && e <= 126);
  if (i == 0) *flag = (__popcll(m) >= 32) ? 1 : 0;
}

// ---------------- weight prep: transpose all GEMM weights to f16 [M][K]
// slots: 0,1 w2[i]; 2,3 lin1[i]; 4,5 lin2[i]; 6,7 lin[i]; 8 out1; 9 out2
__global__ __launch_bounds__(256) void prep_kernel(
    const void* __restrict__ w2, const void* __restrict__ lin1,
    const void* __restrict__ lin2, const void* __restrict__ linw,
    const void* __restrict__ o1w, const void* __restrict__ o2w,
    _Float16* __restrict__ Wt, const int* __restrict__ flag) {
  int isbf = *flag;
  int slot = blockIdx.y;
  const void* src; size_t off = 0; int K = 128, M = 128;
  switch (slot) {
    case 0: src = w2;   off = 0;     break;
    case 1: src = w2;   off = 16384; break;
    case 2: src = lin1; off = 0;     break;
    case 3: src = lin1; off = 16384; break;
    case 4: src = lin2; off = 0;     break;
    case 5: src = lin2; off = 16384; break;
    case 6: src = linw; off = 0;     break;
    case 7: src = linw; off = 16384; break;
    case 8: src = o1w;  M = 64;      break;
    default: src = o2w; K = 64;      break;
  }
  int t = blockIdx.x * 256 + threadIdx.x;
  if (t >= K * M) return;
  int m = t / K, k = t - m * K;
  Wt[(size_t)slot * 16384 + t] = (_Float16)ldf(src, off + (size_t)k * M + m, isbf);
}

// ---------------- table stage 1: act[i][row][h] = ssp(rbf(row)@w1 + b1), f16
__global__ __launch_bounds__(256) void act_kernel(
    const void* __restrict__ w1, const void* __restrict__ b1,
    _Float16* __restrict__ act, const int* __restrict__ flag) {
  int isbf = *flag;
  int idx = blockIdx.x * 256 + threadIdx.x;
  int hh = idx & 127;
  int row = (idx >> 7) % NROWS;
  int i = (idx >> 7) / NROWS;
  if (i >= 2) return;
  float d = (float)row * (DMAXV / (float)NBINS);
  const float delta = 10.0f / 9.0f;
  const float coeff = -0.5f / (delta * delta);
  float u = ldf(b1, i * 128 + hh, isbf);
  #pragma unroll
  for (int g = 0; g < 10; g++) {
    float off = (float)g * delta;
    float r = expf(coeff * (d - off) * (d - off));
    u += r * ldf(w1, (size_t)(i * 10 + g) * 128 + hh, isbf);
  }
  act[idx] = (_Float16)sspf(u);
}

// ---------------- GEMM: out[N,MD] = op(A[N,KD] @ Wt^T (+bias)) (*C) (+resid), f16
// Wt is pre-transposed f16 [MD][KD]. 256 thr = 4 waves, wave: 32 rows x MD cols.
template <int KD, int MD, bool BIAS, bool ACT, bool RES, bool CMUL>
__global__ __launch_bounds__(256) void gemm_kernel(
    const _Float16* __restrict__ A, const _Float16* __restrict__ Wt,
    const void* __restrict__ bias, size_t boff, const _Float16* __restrict__ resid,
    _Float16* __restrict__ out, int nrows, const int* __restrict__ flag) {
  __shared__ __align__(16) _Float16 wT[MD][KD + 8];
  int t = threadIdx.x;
  constexpr int CH = MD * KD / 8;
  #pragma unroll
  for (int idx = t; idx < CH; idx += 256) {
    int m = idx / (KD / 8), kc = idx - m * (KD / 8);
    *(half8*)&wT[m][kc * 8] = *(const half8*)(Wt + (size_t)idx * 8);
  }
  __syncthreads();
  int wave = t >> 6, lane = t & 63;
  int quad = lane >> 4, l16 = lane & 15;
  int row0 = blockIdx.x * 128 + wave * 32;
  constexpr int NT = MD / 16;
  f32x4 acc0[NT] = {}, acc1[NT] = {};
  int r0 = row0 + l16, r1 = row0 + 16 + l16;
  if (r0 >= nrows) r0 = nrows - 1;   // clamp: D row depends only on A row
  if (r1 >= nrows) r1 = nrows - 1;
  const _Float16* ap0 = A + (size_t)r0 * KD;
  const _Float16* ap1 = A + (size_t)r1 * KD;
  #pragma unroll
  for (int ks = 0; ks < KD / 32; ks++) {
    int kb = ks * 32 + quad * 8;
    half8 a0 = *(const half8*)(ap0 + kb);
    half8 a1 = *(const half8*)(ap1 + kb);
    #pragma unroll
    for (int ct = 0; ct < NT; ct++) {
      half8 b = *(const half8*)&wT[ct * 16 + l16][kb];
      acc0[ct] = __builtin_amdgcn_mfma_f32_16x16x32_f16(a0, b, acc0[ct], 0, 0, 0);
      acc1[ct] = __builtin_amdgcn_mfma_f32_16x16x32_f16(a1, b, acc1[ct], 0, 0, 0);
    }
  }
  int isbf = *flag;
  #pragma unroll
  for (int ct = 0; ct < NT; ct++) {
    int col = ct * 16 + l16;
    float bv = BIAS ? ldf(bias, boff + col, isbf) : 0.0f;
    #pragma unroll
    for (int rt = 0; rt < 2; rt++) {
      #pragma unroll
      for (int r = 0; r < 4; r++) {
        int row = row0 + rt * 16 + quad * 4 + r;
        if (row < nrows) {
          float v = (rt ? acc1[ct][r] : acc0[ct][r]) + bv;
          if (ACT) v = sspf(v);
          if (CMUL) {
            float d = (float)row * (DMAXV / (float)NBINS);
            v *= 0.5f * (cosf(d * (3.14159265358979323846f / 10.0f)) + 1.0f);
          }
          if (RES) v += (float)resid[(size_t)row * MD + col];
          out[(size_t)row * MD + col] = (_Float16)v;
        }
      }
    }
  }
}

// ---------------- edge pass 1: dst histogram
__global__ __launch_bounds__(256) void edge_pass1_kernel(
    const int* __restrict__ ei, int* __restrict__ count, int E) {
  int e = blockIdx.x * 256 + threadIdx.x;
  if (e >= E) return;
  atomicAdd(&count[ei[E + e]], 1);
}

// ---------------- scan phase 1: per-block sums (coalesced)
__global__ __launch_bounds__(256) void scan1_kernel(
    const int* __restrict__ count, int* __restrict__ bsum, int n) {
  __shared__ int red[256];
  int t = threadIdx.x, i = blockIdx.x * 256 + t;
  red[t] = (i < n) ? count[i] : 0;
  __syncthreads();
  for (int s = 128; s > 0; s >>= 1) {
    if (t < s) red[t] += red[t + s];
    __syncthreads();
  }
  if (t == 0) bsum[blockIdx.x] = red[0];
}

// ---------------- scan phase 2: scan block sums (nb <= 256), writes offs[n]
__global__ __launch_bounds__(256) void scan2_kernel(
    const int* __restrict__ bsum, int* __restrict__ bbase, int nb,
    int* __restrict__ offs_n) {
  __shared__ int sc[256];
  int t = threadIdx.x;
  int v = (t < nb) ? bsum[t] : 0;
  sc[t] = v;
  __syncthreads();
  for (int s = 1; s < 256; s <<= 1) {
    int u = (t >= s) ? sc[t - s] : 0;
    __syncthreads();
    sc[t] += u;
    __syncthreads();
  }
  if (t < nb) bbase[t] = sc[t] - v;
  if (t == 255) *offs_n = sc[255];
}

// ---------------- scan phase 3: per-block exclusive scan + base (coalesced)
__global__ __launch_bounds__(256) void scan3_kernel(
    const int* __restrict__ count, const int* __restrict__ bbase,
    int* __restrict__ offs, int n) {
  __shared__ int sc[256];
  int t = threadIdx.x, i = blockIdx.x * 256 + t;
  int v = (i < n) ? count[i] : 0;
  sc[t] = v;
  __syncthreads();
  for (int s = 1; s < 256; s <<= 1) {
    int u = (t >= s) ? sc[t - s] : 0;
    __syncthreads();
    sc[t] += u;
    __syncthreads();
  }
  if (i < n) offs[i] = bbase[blockIdx.x] + sc[t] - v;
}

// ---------------- edge pass 2: distance -> nearest bin, place (src<<13|bin) by dst
__global__ __launch_bounds__(256) void edge_pass2_kernel(
    const int* __restrict__ ei, const void* __restrict__ pos,
    const int* __restrict__ offs, int* __restrict__ cur,
    unsigned int* __restrict__ pk, int E, const int* __restrict__ flag) {
  int isbf = *flag;
  int e = blockIdx.x * 256 + threadIdx.x;
  if (e >= E) return;
  int s = ei[e], d = ei[E + e];
  float ax = ldf(pos, s * 3 + 0, isbf), ay = ldf(pos, s * 3 + 1, isbf), az = ldf(pos, s * 3 + 2, isbf);
  float bx = ldf(pos, d * 3 + 0, isbf), by = ldf(pos, d * 3 + 1, isbf), bz = ldf(pos, d * 3 + 2, isbf);
  float dx = ax - bx, dy = ay - by, dz = az - bz;
  float dist = sqrtf(dx * dx + dy * dy + dz * dz);
  int q = (int)(dist * ((float)NBINS / DMAXV) + 0.5f);  // nearest bin
  if (q > NBINS) q = NBINS;
  int p = offs[d] + atomicAdd(&cur[d], 1);
  pk[p] = ((unsigned int)s << 13) | (unsigned int)q;
}

// ---------------- h = emb[z]  (f16)
__global__ __launch_bounds__(256) void embed_kernel(
    const void* __restrict__ emb, const int* __restrict__ z,
    _Float16* __restrict__ h, int total, const int* __restrict__ flag) {
  int isbf = *flag;
  int i = blockIdx.x * 256 + threadIdx.x;
  if (i >= total) return;
  int n = i >> 7, c = i & 127;
  h[i] = (_Float16)ldf(emb, (size_t)z[n] * 128 + c, isbf);
}

// ---------------- CFConv aggregate: one wave per dst, nearest-bin table
__global__ __launch_bounds__(256) void aggregate_kernel(
    const _Float16* __restrict__ xj, const _Float16* __restrict__ table,
    const unsigned int* __restrict__ pk, const int* __restrict__ offs,
    _Float16* __restrict__ agg, int n) {
  int wave = threadIdx.x >> 6, lane = threadIdx.x & 63;
  int dst = blockIdx.x * 4 + wave;
  if (dst >= n) return;
  int beg = offs[dst], end = offs[dst + 1];
  float accx = 0.f, accy = 0.f;
  int c2 = lane * 2;
  #pragma unroll 2
  for (int e = beg; e < end; e++) {
    unsigned int v = pk[e];           // wave-uniform address -> broadcast load
    int src = (int)(v >> 13);
    int bin = (int)(v & 8191u);
    h2 tv = *(const h2*)(table + ((size_t)bin << 7) + c2);
    h2 xv = *(const h2*)(xj + ((size_t)src << 7) + c2);
    accx += (float)xv.x * (float)tv.x;
    accy += (float)xv.y * (float)tv.y;
  }
  h2 o; o.x = (_Float16)accx; o.y = (_Float16)accy;
  *(h2*)(agg + ((size_t)dst << 7) + c2) = o;
}

// ---------------- batch pooling (batch sorted): per-block run-length sums
__global__ __launch_bounds__(128) void pool_kernel(
    const _Float16* __restrict__ t2, const int* __restrict__ batch,
    float* __restrict__ pooled, int n) {
  int c = threadIdx.x;
  int r0 = blockIdx.x * 128, r1 = min(r0 + 128, n);
  float acc = 0.f;
  int cur = batch[r0];
  for (int r = r0; r < r1; r++) {
    int b = batch[r];  // wave-uniform
    if (b != cur) { atomicAdd(&pooled[cur * 128 + c], acc); acc = 0.f; cur = b; }
    acc += (float)t2[(size_t)r * 128 + c];
  }
  atomicAdd(&pooled[cur * 128 + c], acc);
}

// ---------------- final: out[B,4] = pooled @ pred_w + pred_b (dual-dtype out)
__global__ __launch_bounds__(256) void final_kernel(
    const float* __restrict__ pooled, const void* __restrict__ pw,
    const void* __restrict__ pb, void* __restrict__ out,
    int total, const int* __restrict__ flag) {
  int isbf = *flag;
  int t = threadIdx.x;
  if (t >= total) return;
  int b = t >> 2, j = t & 3;
  float s = ldf(pb, j, isbf);
  for (int k = 0; k < 128; k++) s += pooled[b * 128 + k] * ldf(pw, k * 4 + j, isbf);
  if (isbf) ((unsigned short*)out)[t] = f2bf(s);
  else      ((float*)out)[t] = s;
}

extern "C" void kernel_launch(void* const* d_in, const int* in_sizes, int n_in,
                              void* d_out, int out_size, void* d_ws, size_t ws_size,
                              hipStream_t stream) {
  const int* z    = (const int*)d_in[0];
  const void* pos = d_in[1];
  const int* batch = (const int*)d_in[2];
  const int* ei   = (const int*)d_in[3];
  const void* emb  = d_in[4];
  const void* w1   = d_in[5];
  const void* b1   = d_in[6];
  const void* w2   = d_in[7];
  const void* b2   = d_in[8];
  const void* lin1 = d_in[9];
  const void* lin2 = d_in[10];
  const void* lin2b= d_in[11];
  const void* linw = d_in[12];
  const void* linb = d_in[13];
  const void* o1w  = d_in[14];
  const void* o1b  = d_in[15];
  const void* o2w  = d_in[16];
  const void* o2b  = d_in[17];
  const void* pw   = d_in[18];
  const void* pb   = d_in[19];

  int N = in_sizes[0];
  int E = in_sizes[3] / 2;
  int NBLK = (N + 255) / 256;

  // workspace carve (256B aligned). Total ~50 MB.
  char* p = (char*)d_ws;
  auto carve = [&](size_t bytes) -> void* {
    void* r = (void*)p;
    p += (bytes + 255) & ~(size_t)255;
    return r;
  };
  int*      flag   = (int*)carve(256);
  _Float16* Wt     = (_Float16*)carve((size_t)10 * 16384 * 2);       // 320 KB
  _Float16* actb   = (_Float16*)carve((size_t)2 * NROWS * 128 * 2);  // 2.1 MB
  _Float16* tables = (_Float16*)carve((size_t)2 * NROWS * 128 * 2);  // 2.1 MB
  unsigned int* pk = (unsigned int*)carve((size_t)E * 4);            // 6.4 MB
  int*   offs   = (int*)carve((size_t)(N + 1) * 4);
  int*   bsum   = (int*)carve((size_t)NBLK * 4);
  int*   bbase  = (int*)carve((size_t)NBLK * 4);
  char*  zbase  = p;                                                 // zero-init start
  int*   count  = (int*)carve((size_t)N * 4);
  int*   count2 = (int*)carve((size_t)N * 4);
  float* pooled = (float*)carve((size_t)64 * 128 * 4);
  size_t zbytes = (size_t)(p - zbase);
  _Float16* h   = (_Float16*)carve((size_t)N * 128 * 2);             // 12.8 MB
  _Float16* xj  = (_Float16*)carve((size_t)N * 128 * 2);             // 12.8 MB (also t1)
  _Float16* agg = (_Float16*)carve((size_t)N * 128 * 2);             // 12.8 MB (also t2)

  hipMemsetAsync(zbase, 0, zbytes, stream);
  detect_kernel<<<1, 64, 0, stream>>>((const unsigned short*)emb, flag);
  prep_kernel<<<dim3(64, 10), 256, 0, stream>>>(w2, lin1, lin2, linw, o1w, o2w, Wt, flag);
  act_kernel<<<(2 * NROWS * 128 + 255) / 256, 256, 0, stream>>>(w1, b1, actb, flag);

  int tblocks = (NROWS + 127) / 128;
  for (int i = 0; i < 2; i++)
    gemm_kernel<128, 128, true, false, false, true><<<tblocks, 256, 0, stream>>>(
        actb + (size_t)i * NROWS * 128, Wt + (size_t)i * 16384,
        b2, (size_t)i * 128, nullptr, tables + (size_t)i * NROWS * 128, NROWS, flag);

  edge_pass1_kernel<<<(E + 255) / 256, 256, 0, stream>>>(ei, count, E);
  scan1_kernel<<<NBLK, 256, 0, stream>>>(count, bsum, N);
  scan2_kernel<<<1, 256, 0, stream>>>(bsum, bbase, NBLK, offs + N);
  scan3_kernel<<<NBLK, 256, 0, stream>>>(count, bbase, offs, N);
  edge_pass2_kernel<<<(E + 255) / 256, 256, 0, stream>>>(ei, pos, offs, count2, pk, E, flag);
  embed_kernel<<<(N * 128 + 255) / 256, 256, 0, stream>>>(emb, z, h, N * 128, flag);

  int gblocks = (N + 127) / 128;
  for (int i = 0; i < 2; i++) {
    gemm_kernel<128, 128, false, false, false, false><<<gblocks, 256, 0, stream>>>(
        h, Wt + (size_t)(2 + i) * 16384, nullptr, 0, nullptr, xj, N, flag);
    aggregate_kernel<<<(N + 3) / 4, 256, 0, stream>>>(
        xj, tables + (size_t)i * NROWS * 128, pk, offs, agg, N);
    gemm_kernel<128, 128, true, true, false, false><<<gblocks, 256, 0, stream>>>(
        agg, Wt + (size_t)(4 + i) * 16384, lin2b, (size_t)i * 128, nullptr, xj, N, flag);
    gemm_kernel<128, 128, true, false, true, false><<<gblocks, 256, 0, stream>>>(
        xj, Wt + (size_t)(6 + i) * 16384, linb, (size_t)i * 128, h, h, N, flag);
  }

  gemm_kernel<128, 64, true, true, false, false><<<gblocks, 256, 0, stream>>>(
      h, Wt + (size_t)8 * 16384, o1b, 0, nullptr, xj, N, flag);       // t1 [N,64]
  gemm_kernel<64, 128, true, false, false, false><<<gblocks, 256, 0, stream>>>(
      xj, Wt + (size_t)9 * 16384, o2b, 0, nullptr, agg, N, flag);     // t2 [N,128]
  pool_kernel<<<(N + 127) / 128, 128, 0, stream>>>(agg, batch, pooled, N);
  final_kernel<<<1, 256, 0, stream>>>(pooled, pw, pb, d_out, out_size, flag);
}

// Round 5
// 647.706 us; speedup vs baseline: 1.3788x; 1.1314x over previous
//
#include <hip/hip_runtime.h>
#include <stdint.h>

// SchNet on MI355X (gfx950). R5:
//  - aggregate: 2 dsts/wave (32 lanes x 4ch, 8B loads), 2-edge unroll -> 4+
//    independent load streams (was latency-bound at 39% VALU, 95us).
//  - dense chains fused row-locally into 3 kernels (K1: emb->lin1; K2: 3 MFMA
//    stages; K3: 4 MFMA stages) with XOR-swizzled 32KB LDS transpose tile and a
//    single re-staged weight buffer (64KB static LDS budget). Saves 8 launches
//    + ~150MB intermediate traffic.
//  - table build (act + 2 padded-LDS GEMMs w/ cos epilogue), counting sort,
//    pool, final as before. Dual-dtype (bf16/f32) inputs via detect_kernel.

#define NBINS 4096
#define NROWS (NBINS + 1)
#define DMAXV 8.6610f   // slightly above sqrt(75)=8.66025

typedef _Float16 half8 __attribute__((ext_vector_type(8)));
typedef _Float16 h4 __attribute__((ext_vector_type(4)));
typedef float f32x4 __attribute__((ext_vector_type(4)));

__device__ __forceinline__ float bf2f(unsigned short u) {
  union { uint32_t i; float f; } v; v.i = ((uint32_t)u) << 16; return v.f;
}
__device__ __forceinline__ unsigned short f2bf(float f) {
  union { float f; uint32_t i; } v; v.f = f;
  uint32_t u = v.i;
  return (unsigned short)((u + 0x7fffu + ((u >> 16) & 1u)) >> 16);
}
__device__ __forceinline__ float ldf(const void* p, size_t i, int isbf) {
  if (isbf) return bf2f(((const unsigned short*)p)[i]);
  return ((const float*)p)[i];
}
__device__ __forceinline__ float sspf(float x) {
  float sp = (x > 15.0f) ? x : log1pf(expf(x));
  return sp - 0.6931471805599453f;
}

// XOR-swizzled index into a [rows][K] f16 LDS tile (8-half chunks).
// b128 reads at 16 consecutive rows land on distinct chunk slots -> <=2-way.
template <int K>
__device__ __forceinline__ int swz(int row, int hc) {
  constexpr int mask = K / 8 - 1;
  return row * K + ((((hc >> 3) ^ (row & mask)) << 3) | (hc & 7));
}

// stage pre-transposed f16 weight [M][K] from global into swizzled LDS
template <int M, int K>
__device__ __forceinline__ void stageW(_Float16* dst, const _Float16* src, int t) {
  constexpr int CH = M * K / 8;
  constexpr int mask = K / 8 - 1;
  for (int idx = t; idx < CH; idx += 256) {
    int m = idx / (K / 8), kc = idx - m * (K / 8);
    *(half8*)&dst[m * K + ((kc ^ (m & mask)) << 3)] = *(const half8*)(src + (size_t)idx * 8);
  }
}

// ---------------- dtype detection (parallel, ballot)
__global__ void detect_kernel(const unsigned short* __restrict__ emb,
                              int* __restrict__ flag) {
  int i = threadIdx.x;
  unsigned short u = emb[2 * i];
  int e = (u >> 7) & 0xFF;
  unsigned long long m = __ballot(e >= 100 && e <= 126);
  if (i == 0) *flag = (__popcll(m) >= 32) ? 1 : 0;
}

// ---------------- weight prep: transpose all GEMM weights to f16 [M][K]
// slots: 0,1 w2[i]; 2,3 lin1[i]; 4,5 lin2[i]; 6,7 lin[i]; 8 out1; 9 out2
__global__ __launch_bounds__(256) void prep_kernel(
    const void* __restrict__ w2, const void* __restrict__ lin1,
    const void* __restrict__ lin2, const void* __restrict__ linw,
    const void* __restrict__ o1w, const void* __restrict__ o2w,
    _Float16* __restrict__ Wt, const int* __restrict__ flag) {
  int isbf = *flag;
  int slot = blockIdx.y;
  const void* src; size_t off = 0; int K = 128, M = 128;
  switch (slot) {
    case 0: src = w2;   off = 0;     break;
    case 1: src = w2;   off = 16384; break;
    case 2: src = lin1; off = 0;     break;
    case 3: src = lin1; off = 16384; break;
    case 4: src = lin2; off = 0;     break;
    case 5: src = lin2; off = 16384; break;
    case 6: src = linw; off = 0;     break;
    case 7: src = linw; off = 16384; break;
    case 8: src = o1w;  M = 64;      break;
    default: src = o2w; K = 64;      break;
  }
  int t = blockIdx.x * 256 + threadIdx.x;
  if (t >= K * M) return;
  int m = t / K, k = t - m * K;
  Wt[(size_t)slot * 16384 + t] = (_Float16)ldf(src, off + (size_t)k * M + m, isbf);
}

// ---------------- table stage 1: act[i][row][h] = ssp(rbf(row)@w1 + b1), f16
__global__ __launch_bounds__(256) void act_kernel(
    const void* __restrict__ w1, const void* __restrict__ b1,
    _Float16* __restrict__ act, const int* __restrict__ flag) {
  int isbf = *flag;
  int idx = blockIdx.x * 256 + threadIdx.x;
  int hh = idx & 127;
  int row = (idx >> 7) % NROWS;
  int i = (idx >> 7) / NROWS;
  if (i >= 2) return;
  float d = (float)row * (DMAXV / (float)NBINS);
  const float delta = 10.0f / 9.0f;
  const float coeff = -0.5f / (delta * delta);
  float u = ldf(b1, i * 128 + hh, isbf);
  #pragma unroll
  for (int g = 0; g < 10; g++) {
    float off = (float)g * delta;
    float r = expf(coeff * (d - off) * (d - off));
    u += r * ldf(w1, (size_t)(i * 10 + g) * 128 + hh, isbf);
  }
  act[idx] = (_Float16)sspf(u);
}

// ---------------- table GEMM: tables = (act @ w2 + b2) * C(d)  (padded LDS)
__global__ __launch_bounds__(256) void tgemm_kernel(
    const _Float16* __restrict__ A, const _Float16* __restrict__ Wt,
    const void* __restrict__ bias, size_t boff,
    _Float16* __restrict__ out, int nrows, const int* __restrict__ flag) {
  __shared__ __align__(16) _Float16 wT[128][136];
  int t = threadIdx.x;
  #pragma unroll
  for (int idx = t; idx < 2048; idx += 256) {
    int m = idx >> 4, kc = idx & 15;
    *(half8*)&wT[m][kc * 8] = *(const half8*)(Wt + (size_t)idx * 8);
  }
  __syncthreads();
  int wave = t >> 6, lane = t & 63, quad = lane >> 4, l16 = lane & 15;
  int row0 = blockIdx.x * 128 + wave * 32;
  f32x4 acc0[8] = {}, acc1[8] = {};
  int r0 = min(row0 + l16, nrows - 1), r1 = min(row0 + 16 + l16, nrows - 1);
  const _Float16* ap0 = A + (size_t)r0 * 128;
  const _Float16* ap1 = A + (size_t)r1 * 128;
  #pragma unroll
  for (int ks = 0; ks < 4; ks++) {
    int kb = ks * 32 + quad * 8;
    half8 a0 = *(const half8*)(ap0 + kb);
    half8 a1 = *(const half8*)(ap1 + kb);
    #pragma unroll
    for (int ct = 0; ct < 8; ct++) {
      half8 b = *(const half8*)&wT[ct * 16 + l16][kb];
      acc0[ct] = __builtin_amdgcn_mfma_f32_16x16x32_f16(a0, b, acc0[ct], 0, 0, 0);
      acc1[ct] = __builtin_amdgcn_mfma_f32_16x16x32_f16(a1, b, acc1[ct], 0, 0, 0);
    }
  }
  int isbf = *flag;
  #pragma unroll
  for (int ct = 0; ct < 8; ct++) {
    int col = ct * 16 + l16;
    float bv = ldf(bias, boff + col, isbf);
    #pragma unroll
    for (int rt = 0; rt < 2; rt++)
      #pragma unroll
      for (int r = 0; r < 4; r++) {
        int row = row0 + rt * 16 + quad * 4 + r;
        if (row < nrows) {
          float d = (float)row * (DMAXV / (float)NBINS);
          float C = 0.5f * (cosf(d * (3.14159265358979323846f / 10.0f)) + 1.0f);
          float v = ((rt ? acc1[ct][r] : acc0[ct][r]) + bv) * C;
          out[(size_t)row * 128 + col] = (_Float16)v;
        }
      }
  }
}

// ---------------- edge pass 1: dst histogram
__global__ __launch_bounds__(256) void edge_pass1_kernel(
    const int* __restrict__ ei, int* __restrict__ count, int E) {
  int e = blockIdx.x * 256 + threadIdx.x;
  if (e >= E) return;
  atomicAdd(&count[ei[E + e]], 1);
}

// ---------------- scan phase 1: per-block sums
__global__ __launch_bounds__(256) void scan1_kernel(
    const int* __restrict__ count, int* __restrict__ bsum, int n) {
  __shared__ int red[256];
  int t = threadIdx.x, i = blockIdx.x * 256 + t;
  red[t] = (i < n) ? count[i] : 0;
  __syncthreads();
  for (int s = 128; s > 0; s >>= 1) {
    if (t < s) red[t] += red[t + s];
    __syncthreads();
  }
  if (t == 0) bsum[blockIdx.x] = red[0];
}

// ---------------- scan phase 2: scan block sums (nb <= 256)
__global__ __launch_bounds__(256) void scan2_kernel(
    const int* __restrict__ bsum, int* __restrict__ bbase, int nb,
    int* __restrict__ offs_n) {
  __shared__ int sc[256];
  int t = threadIdx.x;
  int v = (t < nb) ? bsum[t] : 0;
  sc[t] = v;
  __syncthreads();
  for (int s = 1; s < 256; s <<= 1) {
    int u = (t >= s) ? sc[t - s] : 0;
    __syncthreads();
    sc[t] += u;
    __syncthreads();
  }
  if (t < nb) bbase[t] = sc[t] - v;
  if (t == 255) *offs_n = sc[255];
}

// ---------------- scan phase 3: per-block exclusive scan + base
__global__ __launch_bounds__(256) void scan3_kernel(
    const int* __restrict__ count, const int* __restrict__ bbase,
    int* __restrict__ offs, int n) {
  __shared__ int sc[256];
  int t = threadIdx.x, i = blockIdx.x * 256 + t;
  int v = (i < n) ? count[i] : 0;
  sc[t] = v;
  __syncthreads();
  for (int s = 1; s < 256; s <<= 1) {
    int u = (t >= s) ? sc[t - s] : 0;
    __syncthreads();
    sc[t] += u;
    __syncthreads();
  }
  if (i < n) offs[i] = bbase[blockIdx.x] + sc[t] - v;
}

// ---------------- edge pass 2: distance -> nearest bin, place (src<<13|bin)
__global__ __launch_bounds__(256) void edge_pass2_kernel(
    const int* __restrict__ ei, const void* __restrict__ pos,
    const int* __restrict__ offs, int* __restrict__ cur,
    unsigned int* __restrict__ pk, int E, const int* __restrict__ flag) {
  int isbf = *flag;
  int e = blockIdx.x * 256 + threadIdx.x;
  if (e >= E) return;
  int s = ei[e], d = ei[E + e];
  float ax = ldf(pos, s * 3 + 0, isbf), ay = ldf(pos, s * 3 + 1, isbf), az = ldf(pos, s * 3 + 2, isbf);
  float bx = ldf(pos, d * 3 + 0, isbf), by = ldf(pos, d * 3 + 1, isbf), bz = ldf(pos, d * 3 + 2, isbf);
  float dx = ax - bx, dy = ay - by, dz = az - bz;
  float dist = sqrtf(dx * dx + dy * dy + dz * dz);
  int q = (int)(dist * ((float)NBINS / DMAXV) + 0.5f);
  if (q > NBINS) q = NBINS;
  int p = offs[d] + atomicAdd(&cur[d], 1);
  pk[p] = ((unsigned int)s << 13) | (unsigned int)q;
}

// ---------------- K1: h = emb[z] (written f16); xj = h @ lin1[0]
__global__ __launch_bounds__(256, 2) void k1_kernel(
    const void* __restrict__ emb, const int* __restrict__ z,
    const _Float16* __restrict__ Wt, _Float16* __restrict__ h,
    _Float16* __restrict__ xj, int nrows, const int* __restrict__ flag) {
  __shared__ __align__(16) _Float16 wS[128 * 128];
  int t = threadIdx.x;
  int isbf = *flag;
  stageW<128, 128>(wS, Wt, t);
  __syncthreads();
  int wave = t >> 6, lane = t & 63, quad = lane >> 4, l16 = lane & 15;
  int row0 = blockIdx.x * 128 + wave * 32;
  int r0 = row0 + l16, r1 = row0 + 16 + l16;
  int z0 = z[min(r0, nrows - 1)], z1 = z[min(r1, nrows - 1)];
  f32x4 acc0[8] = {}, acc1[8] = {};
  #pragma unroll
  for (int ks = 0; ks < 4; ks++) {
    int kb = ks * 32 + quad * 8;
    half8 a0, a1;
    #pragma unroll
    for (int j = 0; j < 8; j++) {
      a0[j] = (_Float16)ldf(emb, (size_t)z0 * 128 + kb + j, isbf);
      a1[j] = (_Float16)ldf(emb, (size_t)z1 * 128 + kb + j, isbf);
    }
    if (r0 < nrows) *(half8*)(h + (size_t)r0 * 128 + kb) = a0;
    if (r1 < nrows) *(half8*)(h + (size_t)r1 * 128 + kb) = a1;
    #pragma unroll
    for (int ct = 0; ct < 8; ct++) {
      half8 b = *(const half8*)&wS[swz<128>(ct * 16 + l16, kb)];
      acc0[ct] = __builtin_amdgcn_mfma_f32_16x16x32_f16(a0, b, acc0[ct], 0, 0, 0);
      acc1[ct] = __builtin_amdgcn_mfma_f32_16x16x32_f16(a1, b, acc1[ct], 0, 0, 0);
    }
  }
  #pragma unroll
  for (int ct = 0; ct < 8; ct++) {
    int col = ct * 16 + l16;
    #pragma unroll
    for (int rt = 0; rt < 2; rt++)
      #pragma unroll
      for (int r = 0; r < 4; r++) {
        int row = row0 + rt * 16 + quad * 4 + r;
        if (row < nrows)
          xj[(size_t)row * 128 + col] = (_Float16)(rt ? acc1[ct][r] : acc0[ct][r]);
      }
  }
}

// ---------------- CFConv aggregate: 2 dsts per wave, 4 ch/lane, unroll 2
__global__ __launch_bounds__(256) void aggregate_kernel(
    const _Float16* __restrict__ xj, const _Float16* __restrict__ table,
    const unsigned int* __restrict__ pk, const int* __restrict__ offs,
    _Float16* __restrict__ agg, int n) {
  int wave = threadIdx.x >> 6, lane = threadIdx.x & 63;
  int half = lane >> 5, l32 = lane & 31;
  int dst = blockIdx.x * 8 + wave * 2 + half;
  if (dst >= n) return;
  int beg = offs[dst], end = offs[dst + 1];
  int c4 = l32 * 4;
  float a0 = 0.f, a1 = 0.f, a2 = 0.f, a3 = 0.f;
  int e = beg;
  for (; e + 2 <= end; e += 2) {
    unsigned int v0 = pk[e], v1 = pk[e + 1];
    h4 t0 = *(const h4*)(table + ((size_t)(v0 & 8191u) << 7) + c4);
    h4 x0 = *(const h4*)(xj + ((size_t)(v0 >> 13) << 7) + c4);
    h4 t1 = *(const h4*)(table + ((size_t)(v1 & 8191u) << 7) + c4);
    h4 x1 = *(const h4*)(xj + ((size_t)(v1 >> 13) << 7) + c4);
    a0 += (float)x0[0] * (float)t0[0] + (float)x1[0] * (float)t1[0];
    a1 += (float)x0[1] * (float)t0[1] + (float)x1[1] * (float)t1[1];
    a2 += (float)x0[2] * (float)t0[2] + (float)x1[2] * (float)t1[2];
    a3 += (float)x0[3] * (float)t0[3] + (float)x1[3] * (float)t1[3];
  }
  if (e < end) {
    unsigned int v0 = pk[e];
    h4 t0 = *(const h4*)(table + ((size_t)(v0 & 8191u) << 7) + c4);
    h4 x0 = *(const h4*)(xj + ((size_t)(v0 >> 13) << 7) + c4);
    a0 += (float)x0[0] * (float)t0[0];
    a1 += (float)x0[1] * (float)t0[1];
    a2 += (float)x0[2] * (float)t0[2];
    a3 += (float)x0[3] * (float)t0[3];
  }
  h4 o; o[0] = (_Float16)a0; o[1] = (_Float16)a1; o[2] = (_Float16)a2; o[3] = (_Float16)a3;
  *(h4*)(agg + ((size_t)dst << 7) + c4) = o;
}

// ---------------- K2: x=ssp(agg@lin2+b); h+=x@lin+b (in place); xj=h@lin1'
__global__ __launch_bounds__(256, 2) void chain3_kernel(
    const _Float16* __restrict__ aggb, _Float16* __restrict__ h,
    const _Float16* __restrict__ WtA, const _Float16* __restrict__ WtB,
    const _Float16* __restrict__ WtC,
    const void* __restrict__ bA, size_t bAo, const void* __restrict__ bB, size_t bBo,
    _Float16* __restrict__ xj, int nrows, const int* __restrict__ flag) {
  __shared__ __align__(16) _Float16 wS[128 * 128];
  __shared__ __align__(16) _Float16 tr[128 * 128];
  int t = threadIdx.x;
  int isbf = *flag;
  int wave = t >> 6, lane = t & 63, quad = lane >> 4, l16 = lane & 15;
  int row0 = blockIdx.x * 128 + wave * 32;
  int wrow = wave * 32;
  int lr0 = wrow + l16, lr1 = wrow + 16 + l16;

  // S1: x = ssp(agg @ A + bA) -> tr
  stageW<128, 128>(wS, WtA, t);
  __syncthreads();
  {
    int r0 = min(row0 + l16, nrows - 1), r1 = min(row0 + 16 + l16, nrows - 1);
    const _Float16* ap0 = aggb + (size_t)r0 * 128;
    const _Float16* ap1 = aggb + (size_t)r1 * 128;
    f32x4 acc0[8] = {}, acc1[8] = {};
    #pragma unroll
    for (int ks = 0; ks < 4; ks++) {
      int kb = ks * 32 + quad * 8;
      half8 a0 = *(const half8*)(ap0 + kb);
      half8 a1 = *(const half8*)(ap1 + kb);
      #pragma unroll
      for (int ct = 0; ct < 8; ct++) {
        half8 b = *(const half8*)&wS[swz<128>(ct * 16 + l16, kb)];
        acc0[ct] = __builtin_amdgcn_mfma_f32_16x16x32_f16(a0, b, acc0[ct], 0, 0, 0);
        acc1[ct] = __builtin_amdgcn_mfma_f32_16x16x32_f16(a1, b, acc1[ct], 0, 0, 0);
      }
    }
    #pragma unroll
    for (int ct = 0; ct < 8; ct++) {
      int col = ct * 16 + l16;
      float bv = ldf(bA, bAo + col, isbf);
      #pragma unroll
      for (int rt = 0; rt < 2; rt++)
        #pragma unroll
        for (int r = 0; r < 4; r++)
          tr[swz<128>(wrow + rt * 16 + quad * 4 + r, col)] =
              (_Float16)sspf((rt ? acc1[ct][r] : acc0[ct][r]) + bv);
    }
  }
  __syncthreads();
  // S2: hnew = h + x @ B + bB  (h in place; also -> tr)
  stageW<128, 128>(wS, WtB, t);
  __syncthreads();
  {
    f32x4 acc0[8] = {}, acc1[8] = {};
    #pragma unroll
    for (int ks = 0; ks < 4; ks++) {
      int kb = ks * 32 + quad * 8;
      half8 a0 = *(const half8*)&tr[swz<128>(lr0, kb)];
      half8 a1 = *(const half8*)&tr[swz<128>(lr1, kb)];
      #pragma unroll
      for (int ct = 0; ct < 8; ct++) {
        half8 b = *(const half8*)&wS[swz<128>(ct * 16 + l16, kb)];
        acc0[ct] = __builtin_amdgcn_mfma_f32_16x16x32_f16(a0, b, acc0[ct], 0, 0, 0);
        acc1[ct] = __builtin_amdgcn_mfma_f32_16x16x32_f16(a1, b, acc1[ct], 0, 0, 0);
      }
    }
    #pragma unroll
    for (int ct = 0; ct < 8; ct++) {
      int col = ct * 16 + l16;
      float bv = ldf(bB, bBo + col, isbf);
      #pragma unroll
      for (int rt = 0; rt < 2; rt++)
        #pragma unroll
        for (int r = 0; r < 4; r++) {
          int row = row0 + rt * 16 + quad * 4 + r;
          float v = (rt ? acc1[ct][r] : acc0[ct][r]) + bv;
          if (row < nrows) {
            size_t idx = (size_t)row * 128 + col;
            v += (float)h[idx];
            h[idx] = (_Float16)v;
          }
          tr[swz<128>(wrow + rt * 16 + quad * 4 + r, col)] = (_Float16)v;
        }
    }
  }
  __syncthreads();
  // S3: xj = hnew @ C
  stageW<128, 128>(wS, WtC, t);
  __syncthreads();
  {
    f32x4 acc0[8] = {}, acc1[8] = {};
    #pragma unroll
    for (int ks = 0; ks < 4; ks++) {
      int kb = ks * 32 + quad * 8;
      half8 a0 = *(const half8*)&tr[swz<128>(lr0, kb)];
      half8 a1 = *(const half8*)&tr[swz<128>(lr1, kb)];
      #pragma unroll
      for (int ct = 0; ct < 8; ct++) {
        half8 b = *(const half8*)&wS[swz<128>(ct * 16 + l16, kb)];
        acc0[ct] = __builtin_amdgcn_mfma_f32_16x16x32_f16(a0, b, acc0[ct], 0, 0, 0);
        acc1[ct] = __builtin_amdgcn_mfma_f32_16x16x32_f16(a1, b, acc1[ct], 0, 0, 0);
      }
    }
    #pragma unroll
    for (int ct = 0; ct < 8; ct++) {
      int col = ct * 16 + l16;
      #pragma unroll
      for (int rt = 0; rt < 2; rt++)
        #pragma unroll
        for (int r = 0; r < 4; r++) {
          int row = row0 + rt * 16 + quad * 4 + r;
          if (row < nrows)
            xj[(size_t)row * 128 + col] = (_Float16)(rt ? acc1[ct][r] : acc0[ct][r]);
        }
    }
  }
}

// ---------------- K3: x=ssp(agg@lin2+b); h2=h+x@lin+b; t1=ssp(h2@o1+b); t2=t1@o2+b
__global__ __launch_bounds__(256, 2) void chain4_kernel(
    const _Float16* __restrict__ aggb, const _Float16* __restrict__ h,
    const _Float16* __restrict__ WtA, const _Float16* __restrict__ WtB,
    const _Float16* __restrict__ WtC, const _Float16* __restrict__ WtD,
    const void* __restrict__ bA, size_t bAo, const void* __restrict__ bB, size_t bBo,
    const void* __restrict__ bC, const void* __restrict__ bD,
    _Float16* __restrict__ t2, int nrows, const int* __restrict__ flag) {
  __shared__ __align__(16) _Float16 wS[128 * 128];
  __shared__ __align__(16) _Float16 tr[128 * 128];
  int t = threadIdx.x;
  int isbf = *flag;
  int wave = t >> 6, lane = t & 63, quad = lane >> 4, l16 = lane & 15;
  int row0 = blockIdx.x * 128 + wave * 32;
  int wrow = wave * 32;
  int lr0 = wrow + l16, lr1 = wrow + 16 + l16;

  // S1: x = ssp(agg @ A + bA) -> tr
  stageW<128, 128>(wS, WtA, t);
  __syncthreads();
  {
    int r0 = min(row0 + l16, nrows - 1), r1 = min(row0 + 16 + l16, nrows - 1);
    const _Float16* ap0 = aggb + (size_t)r0 * 128;
    const _Float16* ap1 = aggb + (size_t)r1 * 128;
    f32x4 acc0[8] = {}, acc1[8] = {};
    #pragma unroll
    for (int ks = 0; ks < 4; ks++) {
      int kb = ks * 32 + quad * 8;
      half8 a0 = *(const half8*)(ap0 + kb);
      half8 a1 = *(const half8*)(ap1 + kb);
      #pragma unroll
      for (int ct = 0; ct < 8; ct++) {
        half8 b = *(const half8*)&wS[swz<128>(ct * 16 + l16, kb)];
        acc0[ct] = __builtin_amdgcn_mfma_f32_16x16x32_f16(a0, b, acc0[ct], 0, 0, 0);
        acc1[ct] = __builtin_amdgcn_mfma_f32_16x16x32_f16(a1, b, acc1[ct], 0, 0, 0);
      }
    }
    #pragma unroll
    for (int ct = 0; ct < 8; ct++) {
      int col = ct * 16 + l16;
      float bv = ldf(bA, bAo + col, isbf);
      #pragma unroll
      for (int rt = 0; rt < 2; rt++)
        #pragma unroll
        for (int r = 0; r < 4; r++)
          tr[swz<128>(wrow + rt * 16 + quad * 4 + r, col)] =
              (_Float16)sspf((rt ? acc1[ct][r] : acc0[ct][r]) + bv);
    }
  }
  __syncthreads();
  // S2: h2 = h + x @ B + bB -> tr (no global write)
  stageW<128, 128>(wS, WtB, t);
  __syncthreads();
  {
    int r0 = min(row0 + l16, nrows - 1);  // unused; keep rows clamped via guards
    (void)r0;
    f32x4 acc0[8] = {}, acc1[8] = {};
    #pragma unroll
    for (int ks = 0; ks < 4; ks++) {
      int kb = ks * 32 + quad * 8;
      half8 a0 = *(const half8*)&tr[swz<128>(lr0, kb)];
      half8 a1 = *(const half8*)&tr[swz<128>(lr1, kb)];
      #pragma unroll
      for (int ct = 0; ct < 8; ct++) {
        half8 b = *(const half8*)&wS[swz<128>(ct * 16 + l16, kb)];
        acc0[ct] = __builtin_amdgcn_mfma_f32_16x16x32_f16(a0, b, acc0[ct], 0, 0, 0);
        acc1[ct] = __builtin_amdgcn_mfma_f32_16x16x32_f16(a1, b, acc1[ct], 0, 0, 0);
      }
    }
    #pragma unroll
    for (int ct = 0; ct < 8; ct++) {
      int col = ct * 16 + l16;
      float bv = ldf(bB, bBo + col, isbf);
      #pragma unroll
      for (int rt = 0; rt < 2; rt++)
        #pragma unroll
        for (int r = 0; r < 4; r++) {
          int row = row0 + rt * 16 + quad * 4 + r;
          float v = (rt ? acc1[ct][r] : acc0[ct][r]) + bv;
          if (row < nrows) v += (float)h[(size_t)row * 128 + col];
          tr[swz<128>(wrow + rt * 16 + quad * 4 + r, col)] = (_Float16)v;
        }
    }
  }
  __syncthreads();
  // S3: t1 = ssp(h2 @ o1 + bC) -> tr cols 0..63
  stageW<64, 128>(wS, WtC, t);
  __syncthreads();
  {
    f32x4 acc0[4] = {}, acc1[4] = {};
    #pragma unroll
    for (int ks = 0; ks < 4; ks++) {
      int kb = ks * 32 + quad * 8;
      half8 a0 = *(const half8*)&tr[swz<128>(lr0, kb)];
      half8 a1 = *(const half8*)&tr[swz<128>(lr1, kb)];
      #pragma unroll
      for (int ct = 0; ct < 4; ct++) {
        half8 b = *(const half8*)&wS[swz<128>(ct * 16 + l16, kb)];
        acc0[ct] = __builtin_amdgcn_mfma_f32_16x16x32_f16(a0, b, acc0[ct], 0, 0, 0);
        acc1[ct] = __builtin_amdgcn_mfma_f32_16x16x32_f16(a1, b, acc1[ct], 0, 0, 0);
      }
    }
    #pragma unroll
    for (int ct = 0; ct < 4; ct++) {
      int col = ct * 16 + l16;
      float bv = ldf(bC, col, isbf);
      #pragma unroll
      for (int rt = 0; rt < 2; rt++)
        #pragma unroll
        for (int r = 0; r < 4; r++)
          tr[swz<128>(wrow + rt * 16 + quad * 4 + r, col)] =
              (_Float16)sspf((rt ? acc1[ct][r] : acc0[ct][r]) + bv);
    }
  }
  __syncthreads();
  // S4: t2 = t1 @ o2 + bD  (K=64)
  stageW<128, 64>(wS, WtD, t);
  __syncthreads();
  {
    f32x4 acc0[8] = {}, acc1[8] = {};
    #pragma unroll
    for (int ks = 0; ks < 2; ks++) {
      int kb = ks * 32 + quad * 8;
      half8 a0 = *(const half8*)&tr[swz<128>(lr0, kb)];
      half8 a1 = *(const half8*)&tr[swz<128>(lr1, kb)];
      #pragma unroll
      for (int ct = 0; ct < 8; ct++) {
        half8 b = *(const half8*)&wS[swz<64>(ct * 16 + l16, kb)];
        acc0[ct] = __builtin_amdgcn_mfma_f32_16x16x32_f16(a0, b, acc0[ct], 0, 0, 0);
        acc1[ct] = __builtin_amdgcn_mfma_f32_16x16x32_f16(a1, b, acc1[ct], 0, 0, 0);
      }
    }
    #pragma unroll
    for (int ct = 0; ct < 8; ct++) {
      int col = ct * 16 + l16;
      float bv = ldf(bD, col, isbf);
      #pragma unroll
      for (int rt = 0; rt < 2; rt++)
        #pragma unroll
        for (int r = 0; r < 4; r++) {
          int row = row0 + rt * 16 + quad * 4 + r;
          if (row < nrows)
            t2[(size_t)row * 128 + col] = (_Float16)((rt ? acc1[ct][r] : acc0[ct][r]) + bv);
        }
    }
  }
}

// ---------------- batch pooling (batch sorted)
__global__ __launch_bounds__(128) void pool_kernel(
    const _Float16* __restrict__ t2, const int* __restrict__ batch,
    float* __restrict__ pooled, int n) {
  int c = threadIdx.x;
  int r0 = blockIdx.x * 128, r1 = min(r0 + 128, n);
  float acc = 0.f;
  int cur = batch[r0];
  for (int r = r0; r < r1; r++) {
    int b = batch[r];
    if (b != cur) { atomicAdd(&pooled[cur * 128 + c], acc); acc = 0.f; cur = b; }
    acc += (float)t2[(size_t)r * 128 + c];
  }
  atomicAdd(&pooled[cur * 128 + c], acc);
}

// ---------------- final: out[B,4] = pooled @ pred_w + pred_b
__global__ __launch_bounds__(256) void final_kernel(
    const float* __restrict__ pooled, const void* __restrict__ pw,
    const void* __restrict__ pb, void* __restrict__ out,
    int total, const int* __restrict__ flag) {
  int isbf = *flag;
  int t = threadIdx.x;
  if (t >= total) return;
  int b = t >> 2, j = t & 3;
  float s = ldf(pb, j, isbf);
  for (int k = 0; k < 128; k++) s += pooled[b * 128 + k] * ldf(pw, k * 4 + j, isbf);
  if (isbf) ((unsigned short*)out)[t] = f2bf(s);
  else      ((float*)out)[t] = s;
}

extern "C" void kernel_launch(void* const* d_in, const int* in_sizes, int n_in,
                              void* d_out, int out_size, void* d_ws, size_t ws_size,
                              hipStream_t stream) {
  const int* z    = (const int*)d_in[0];
  const void* pos = d_in[1];
  const int* batch = (const int*)d_in[2];
  const int* ei   = (const int*)d_in[3];
  const void* emb  = d_in[4];
  const void* w1   = d_in[5];
  const void* b1   = d_in[6];
  const void* w2   = d_in[7];
  const void* b2   = d_in[8];
  const void* lin1 = d_in[9];
  const void* lin2 = d_in[10];
  const void* lin2b= d_in[11];
  const void* linw = d_in[12];
  const void* linb = d_in[13];
  const void* o1w  = d_in[14];
  const void* o1b  = d_in[15];
  const void* o2w  = d_in[16];
  const void* o2b  = d_in[17];
  const void* pw   = d_in[18];
  const void* pb   = d_in[19];

  int N = in_sizes[0];
  int E = in_sizes[3] / 2;
  int NBLK = (N + 255) / 256;

  char* p = (char*)d_ws;
  auto carve = [&](size_t bytes) -> void* {
    void* r = (void*)p;
    p += (bytes + 255) & ~(size_t)255;
    return r;
  };
  int*      flag   = (int*)carve(256);
  _Float16* Wt     = (_Float16*)carve((size_t)10 * 16384 * 2);
  _Float16* actb   = (_Float16*)carve((size_t)2 * NROWS * 128 * 2);
  _Float16* tables = (_Float16*)carve((size_t)2 * NROWS * 128 * 2);
  unsigned int* pk = (unsigned int*)carve((size_t)E * 4);
  int*   offs   = (int*)carve((size_t)(N + 1) * 4);
  int*   bsum   = (int*)carve((size_t)NBLK * 4);
  int*   bbase  = (int*)carve((size_t)NBLK * 4);
  char*  zbase  = p;
  int*   count  = (int*)carve((size_t)N * 4);
  int*   count2 = (int*)carve((size_t)N * 4);
  float* pooled = (float*)carve((size_t)64 * 128 * 4);
  size_t zbytes = (size_t)(p - zbase);
  _Float16* h   = (_Float16*)carve((size_t)N * 128 * 2);
  _Float16* xj  = (_Float16*)carve((size_t)N * 128 * 2);   // xj0/xj1, then t2
  _Float16* agg = (_Float16*)carve((size_t)N * 128 * 2);   // agg0/agg1

  hipMemsetAsync(zbase, 0, zbytes, stream);
  detect_kernel<<<1, 64, 0, stream>>>((const unsigned short*)emb, flag);
  prep_kernel<<<dim3(64, 10), 256, 0, stream>>>(w2, lin1, lin2, linw, o1w, o2w, Wt, flag);
  act_kernel<<<(2 * NROWS * 128 + 255) / 256, 256, 0, stream>>>(w1, b1, actb, flag);

  int tblocks = (NROWS + 127) / 128;
  for (int i = 0; i < 2; i++)
    tgemm_kernel<<<tblocks, 256, 0, stream>>>(
        actb + (size_t)i * NROWS * 128, Wt + (size_t)i * 16384,
        b2, (size_t)i * 128, tables + (size_t)i * NROWS * 128, NROWS, flag);

  edge_pass1_kernel<<<(E + 255) / 256, 256, 0, stream>>>(ei, count, E);
  scan1_kernel<<<NBLK, 256, 0, stream>>>(count, bsum, N);
  scan2_kernel<<<1, 256, 0, stream>>>(bsum, bbase, NBLK, offs + N);
  scan3_kernel<<<NBLK, 256, 0, stream>>>(count, bbase, offs, N);
  edge_pass2_kernel<<<(E + 255) / 256, 256, 0, stream>>>(ei, pos, offs, count2, pk, E, flag);

  int gblocks = (N + 127) / 128;
  k1_kernel<<<gblocks, 256, 0, stream>>>(emb, z, Wt + (size_t)2 * 16384, h, xj, N, flag);
  aggregate_kernel<<<(N + 7) / 8, 256, 0, stream>>>(xj, tables, pk, offs, agg, N);
  chain3_kernel<<<gblocks, 256, 0, stream>>>(
      agg, h, Wt + (size_t)4 * 16384, Wt + (size_t)6 * 16384, Wt + (size_t)3 * 16384,
      lin2b, 0, linb, 0, xj, N, flag);
  aggregate_kernel<<<(N + 7) / 8, 256, 0, stream>>>(
      xj, tables + (size_t)NROWS * 128, pk, offs, agg, N);
  chain4_kernel<<<gblocks, 256, 0, stream>>>(
      agg, h, Wt + (size_t)5 * 16384, Wt + (size_t)7 * 16384,
      Wt + (size_t)8 * 16384, Wt + (size_t)9 * 16384,
      lin2b, 128, linb, 128, o1b, o2b, xj, N, flag);
  pool_kernel<<<(N + 127) / 128, 128, 0, stream>>>(xj, batch, pooled, N);
  final_kernel<<<1, 256, 0, stream>>>(pooled, pw, pb, d_out, out_size, flag);
}